// Round 2
// baseline (2977.698 us; speedup 1.0000x reference)
//
#include <hip/hip_runtime.h>
#include <hip/hip_bf16.h>
#include <math.h>

// ---------- types ----------
typedef __bf16 bf16x8 __attribute__((ext_vector_type(8)));
typedef float  f32x4  __attribute__((ext_vector_type(4)));
typedef unsigned short us8 __attribute__((ext_vector_type(8)));
typedef unsigned short us4 __attribute__((ext_vector_type(4)));
typedef unsigned short ush;

__device__ __forceinline__ unsigned short f2bf(float x) {
  unsigned int u = __float_as_uint(x);
  u += 0x7FFFu + ((u >> 16) & 1u);          // RNE
  return (unsigned short)(u >> 16);
}
__device__ __forceinline__ float bf2f(unsigned short v) {
  return __uint_as_float(((unsigned int)v) << 16);
}
// tanh-form GELU: max |diff vs erf-gelu| ~1e-3, harmless vs threshold
__device__ __forceinline__ float gelu_t(float x) {
  float y = 0.7978845608028654f * x * (1.0f + 0.044715f * x * x);
  float e = __expf(2.0f * y);
  return x - x / (e + 1.0f);
}

// Problem constants: B=32, V=4, P=784, D=768; rows n = bp*4+v, bp=b*784+p
// NROW = 100352 = 392*256

// ---------- f32 -> bf16 convert (weights) ----------
__global__ __launch_bounds__(256) void conv_f32_bf16(const float* __restrict__ s,
                                                     unsigned short* __restrict__ d, int n4) {
  int i = blockIdx.x * 256 + threadIdx.x;
  if (i >= n4) return;
  float4 f = ((const float4*)s)[i];
  ushort4 u;
  u.x = f2bf(f.x); u.y = f2bf(f.y); u.z = f2bf(f.z); u.w = f2bf(f.w);
  ((ushort4*)d)[i] = u;
}

// ---------- LayerNorm: read permuted fp32 row, write bf16 row ----------
__global__ __launch_bounds__(256) void ln_kernel(const float* __restrict__ src,
                                                 const float* __restrict__ w,
                                                 const float* __restrict__ b,
                                                 unsigned short* __restrict__ dst) {
  const int wv = threadIdx.x >> 6;
  const int lane = threadIdx.x & 63;
  const int n = blockIdx.x * 4 + wv;            // token row 0..100351
  const int bp = n >> 2, v = n & 3;
  const int bb = bp / 784, p = bp - bb * 784;
  const float* row = src + ((size_t)bb * 3136 + (size_t)v * 784 + p) * 768;
  float4 x0 = ((const float4*)row)[lane];
  float4 x1 = ((const float4*)row)[lane + 64];
  float4 x2 = ((const float4*)row)[lane + 128];
  float s  = x0.x + x0.y + x0.z + x0.w + x1.x + x1.y + x1.z + x1.w
           + x2.x + x2.y + x2.z + x2.w;
  float ss = x0.x*x0.x + x0.y*x0.y + x0.z*x0.z + x0.w*x0.w
           + x1.x*x1.x + x1.y*x1.y + x1.z*x1.z + x1.w*x1.w
           + x2.x*x2.x + x2.y*x2.y + x2.z*x2.z + x2.w*x2.w;
  #pragma unroll
  for (int off = 32; off > 0; off >>= 1) {
    s  += __shfl_xor(s,  off, 64);
    ss += __shfl_xor(ss, off, 64);
  }
  const float mu   = s * (1.0f / 768.0f);
  const float rstd = rsqrtf(ss * (1.0f / 768.0f) - mu * mu + 1e-5f);
  unsigned short* drow = dst + (size_t)n * 768;
  #pragma unroll
  for (int seg = 0; seg < 3; ++seg) {
    float4 xs = (seg == 0) ? x0 : (seg == 1) ? x1 : x2;
    float4 w4 = ((const float4*)w)[lane + seg * 64];
    float4 b4 = ((const float4*)b)[lane + seg * 64];
    ushort4 u;
    u.x = f2bf((xs.x - mu) * rstd * w4.x + b4.x);
    u.y = f2bf((xs.y - mu) * rstd * w4.y + b4.y);
    u.z = f2bf((xs.z - mu) * rstd * w4.z + b4.z);
    u.w = f2bf((xs.w - mu) * rstd * w4.w + b4.w);
    ((ushort4*)drow)[lane + seg * 64] = u;
  }
}

// =====================================================================
// PERSISTENT 256x256-tile GEMM, BK=64, 8 waves (2M x 4N), 8-phase
// counted-vmcnt schedule that NEVER drains across output tiles.
//
// grid = 256 blocks, 1/CU (128 KiB LDS). Block bid: xcd=bid&7, cu=bid>>3.
// Tile list: pos = xcd*(nwg/8) + cu + 32*k  (XCD-contiguous pos range,
// bx-fastest order -> A panel L2 reuse within an XCD; perf heuristic).
//
// Flat K-step stream s over (tile, k)-pairs; per step (parity PAR=s&1,
// NT even so tile starts are always parity 0):
//   q0: ds_read A(h0)+B(h0); stage A1(s+1); bar; MFMA00; vmcnt(6); bar
//   q1: ds_read B(h1);       stage B1(s+1); bar; MFMA01;           bar
//   q2: ds_read A(h1);       stage A0(s+2); bar; MFMA10;           bar
//   q3: (B frags reused);    stage B0(s+2); bar; MFMA11; vmcnt(8); bar
// Invariant (loads, 2/stage): after q3's vmcnt(8) exactly A1(s+1),B1(s+1),
// A0(s+2),B0(s+2) are in flight. vmcnt(6)@q0 retires A1(s),B1(s) before
// q1/q2 read them. Tail (last tile only): q3@NT-2 -> vmcnt(4),
// q0@NT-1 -> vmcnt(0). Stage slots cross tile boundaries seamlessly.
//
// Epilogue: direct from acc (C frag: row=quad*4+r, col=l16) -- no LDS,
// no barriers; runs after the tile's last MFMA while the next tile's
// staged loads land. Epilogue stores pollute vmcnt -> the next q0's
// vmcnt(6) over-waits once per tile (accepted, ~5%).
// =====================================================================

#define BARX() do { asm volatile("" ::: "memory"); \
                    __builtin_amdgcn_s_barrier();  \
                    asm volatile("" ::: "memory"); } while (0)
#define WAITVM(N) asm volatile("s_waitcnt vmcnt(" #N ")" ::: "memory")

// stage one 128-row half (16 KiB) of A (ISB=0) or B (ISB=1) into buffer PAR
#define STAGE2(ISB, HALF, PAR, PTR) do {                                      \
  const int _l0 = ((PAR) << 15) + ((ISB) ? 16384 : 0) + ((HALF) << 13)        \
                + (w << 9);                                                   \
  const ush* _g = (PTR) + (size_t)(((HALF) << 7) + (w << 3)) * K;             \
  __builtin_amdgcn_global_load_lds(                                           \
      (const __attribute__((address_space(1))) void*)_g,                      \
      (__attribute__((address_space(3))) void*)(smem + _l0), 16, 0, 0);       \
  __builtin_amdgcn_global_load_lds(                                           \
      (const __attribute__((address_space(1))) void*)(_g + ((size_t)K << 6)), \
      (__attribute__((address_space(3))) void*)(smem + _l0 + 4096), 16, 0, 0);\
} while (0)

#define LDA(HM) do {                                                          \
  _Pragma("unroll")                                                           \
  for (int mi4 = 0; mi4 < 4; ++mi4) {                                         \
    const int m = wm * 64 + (HM) * 128 + mi4 * 16 + l16;                      \
    _Pragma("unroll")                                                         \
    for (int kk = 0; kk < 2; ++kk) {                                          \
      const int q = kk * 4 + quad;                                            \
      af[mi4][kk] = *(const bf16x8*)(smem + aofs + m * 64 + ((q ^ l7) << 3)); \
    }                                                                         \
  }                                                                           \
} while (0)

#define LDB(HN, BF) do {                                                      \
  _Pragma("unroll")                                                           \
  for (int ni2 = 0; ni2 < 2; ++ni2) {                                         \
    const int n = wn * 32 + (HN) * 128 + ni2 * 16 + l16;                      \
    _Pragma("unroll")                                                         \
    for (int kk = 0; kk < 2; ++kk) {                                          \
      const int q = kk * 4 + quad;                                            \
      BF[ni2][kk] = *(const bf16x8*)(smem + bofs + n * 64 + ((q ^ l7) << 3)); \
    }                                                                         \
  }                                                                           \
} while (0)

#define MFMAC(HM, HN, BF) do {                                                \
  __builtin_amdgcn_s_setprio(1);                                              \
  _Pragma("unroll")                                                           \
  for (int mi4 = 0; mi4 < 4; ++mi4)                                           \
    _Pragma("unroll")                                                         \
    for (int ni2 = 0; ni2 < 2; ++ni2)                                         \
      _Pragma("unroll")                                                       \
      for (int kk = 0; kk < 2; ++kk)                                          \
        acc[(HM)*4 + mi4][(HN)*2 + ni2] = __builtin_amdgcn_mfma_f32_16x16x32_bf16( \
            af[mi4][kk], BF[ni2][kk], acc[(HM)*4 + mi4][(HN)*2 + ni2], 0, 0, 0); \
  __builtin_amdgcn_s_setprio(0);                                              \
} while (0)

#define ZEROACC() do {                                                        \
  _Pragma("unroll")                                                           \
  for (int _i = 0; _i < 8; ++_i)                                              \
    _Pragma("unroll")                                                         \
    for (int _j = 0; _j < 4; ++_j) { f32x4 _z = {0.f,0.f,0.f,0.f}; acc[_i][_j] = _z; } \
} while (0)

// advance slot2 (stage stream for step s+2) by one K-step
#define ADV2() do {                                                           \
  k2 += 64;                                                                   \
  if (k2 < K) { if (live2) { pA2 += 64; pB2 += 64; } }                        \
  else {                                                                      \
    k2 = 0; pos2 += 32;                                                       \
    if (pos2 < pos_end) {                                                     \
      const int _by = pos2 / gx, _bx = pos2 - _by * gx;                       \
      pA2 = A  + (size_t)(_by * 256 + r8) * K + swo;                          \
      pB2 = Bm + (size_t)(_bx * 256 + r8) * K + swo;                          \
      live2 = true;                                                           \
    } else { live2 = false; }                                                 \
  }                                                                           \
} while (0)

#define SHIFT() do {                                                          \
  pA1 = pA2; pB1 = pB2; live1 = live2; k1 = k2; pos1 = pos2;                  \
  ADV2();                                                                     \
} while (0)

// one K-step; PAR = compile-time buffer parity (== kc&1, NT even)
#define STEP(PAR) do {                                                        \
  const int aofs = (PAR) << 15;                                               \
  const int bofs = aofs + 16384;                                              \
  const bool lastT = (pos_c + 32 >= pos_end);                                 \
  /* q0 */                                                                    \
  LDA(0); LDB(0, bf0);                                                        \
  if (live1) { STAGE2(0, 1, (PAR) ^ 1, pA1); }                                \
  BARX();                                                                     \
  MFMAC(0, 0, bf0);                                                           \
  if (lastT && kc == NT - 1) { WAITVM(0); } else { WAITVM(6); }               \
  BARX();                                                                     \
  /* q1 */                                                                    \
  LDB(1, bf1);                                                                \
  if (live1) { STAGE2(1, 1, (PAR) ^ 1, pB1); }                                \
  BARX();                                                                     \
  MFMAC(0, 1, bf1);                                                           \
  BARX();                                                                     \
  /* q2 */                                                                    \
  LDA(1);                                                                     \
  if (live2) { STAGE2(0, 0, (PAR), pA2); }                                    \
  BARX();                                                                     \
  MFMAC(1, 0, bf0);                                                           \
  BARX();                                                                     \
  /* q3 (B frags reused) */                                                   \
  if (live2) { STAGE2(1, 0, (PAR), pB2); }                                    \
  BARX();                                                                     \
  MFMAC(1, 1, bf1);                                                           \
  if (!lastT || kc <= NT - 3) { WAITVM(8); }                                  \
  else if (kc == NT - 2) { WAITVM(4); }                                       \
  BARX();                                                                     \
} while (0)

// direct-from-acc epilogue; C row = rb0 + hm2*128 + mi4*16 + r (rb0 % 4 == 0
// so v = r), col = cb0 + hn*128 + ni2*16
#define EPILOGUE() do {                                                       \
  const int rb0 = by_c * 256 + wm * 64 + quad * 4;                            \
  const int cb0 = bx_c * 256 + wn * 32 + l16;                                 \
  if (EPI == 1 || EPI == 3) {                                                 \
    size_t rowb[8];                                                           \
    _Pragma("unroll")                                                         \
    for (int hm2 = 0; hm2 < 2; ++hm2)                                         \
      _Pragma("unroll")                                                       \
      for (int mi4 = 0; mi4 < 4; ++mi4) {                                     \
        const int bp = (rb0 + hm2 * 128 + mi4 * 16) >> 2;                     \
        const int bb = bp / 784, p = bp - bb * 784;                           \
        rowb[hm2 * 4 + mi4] = ((size_t)bb * 3136 + p) * 768;                  \
      }                                                                       \
    _Pragma("unroll")                                                         \
    for (int hn = 0; hn < 2; ++hn)                                            \
      _Pragma("unroll")                                                       \
      for (int ni2 = 0; ni2 < 2; ++ni2) {                                     \
        const int col = cb0 + hn * 128 + ni2 * 16;                            \
        const float bv = bias[col];                                           \
        _Pragma("unroll")                                                     \
        for (int hm2 = 0; hm2 < 2; ++hm2)                                     \
          _Pragma("unroll")                                                   \
          for (int mi4 = 0; mi4 < 4; ++mi4) {                                 \
            const size_t ba = rowb[hm2 * 4 + mi4] + col;                      \
            _Pragma("unroll")                                                 \
            for (int r = 0; r < 4; ++r) {                                     \
              const size_t ad = ba + (size_t)r * 602112;                      \
              ((float*)outp)[ad] = acc[hm2*4+mi4][hn*2+ni2][r] + bv + aux[ad];\
            }                                                                 \
          }                                                                   \
      }                                                                       \
  } else if (EPI == 0) {                                                      \
    _Pragma("unroll")                                                         \
    for (int hn = 0; hn < 2; ++hn)                                            \
      _Pragma("unroll")                                                       \
      for (int ni2 = 0; ni2 < 2; ++ni2) {                                     \
        const int col = cb0 + hn * 128 + ni2 * 16;                            \
        const int seg = col / 768;                                            \
        const int c2  = col - seg * 768;                                      \
        const int hh  = c2 / 96;                                              \
        const int dd  = c2 - hh * 96;                                         \
        const int colb = seg * 3072 + hh * 384 + dd;                          \
        const float bv = bias[col];                                           \
        _Pragma("unroll")                                                     \
        for (int hm2 = 0; hm2 < 2; ++hm2)                                     \
          _Pragma("unroll")                                                   \
          for (int mi4 = 0; mi4 < 4; ++mi4) {                                 \
            const int bp = (rb0 + hm2 * 128 + mi4 * 16) >> 2;                 \
            unsigned short* ob = (unsigned short*)outp + (size_t)bp * 9216 + colb; \
            _Pragma("unroll")                                                 \
            for (int r = 0; r < 4; ++r)                                       \
              ob[r * 96] = f2bf(acc[hm2*4+mi4][hn*2+ni2][r] + bv);            \
          }                                                                   \
      }                                                                       \
  } else { /* EPI == 2: gelu -> bf16 row-major */                             \
    _Pragma("unroll")                                                         \
    for (int hn = 0; hn < 2; ++hn)                                            \
      _Pragma("unroll")                                                       \
      for (int ni2 = 0; ni2 < 2; ++ni2) {                                     \
        const int col = cb0 + hn * 128 + ni2 * 16;                            \
        const float bv = bias[col];                                           \
        _Pragma("unroll")                                                     \
        for (int hm2 = 0; hm2 < 2; ++hm2)                                     \
          _Pragma("unroll")                                                   \
          for (int mi4 = 0; mi4 < 4; ++mi4) {                                 \
            const int rr = rb0 + hm2 * 128 + mi4 * 16;                        \
            unsigned short* ob = (unsigned short*)outp + (size_t)rr * N + col;\
            _Pragma("unroll")                                                 \
            for (int r = 0; r < 4; ++r)                                       \
              ob[(size_t)r * N] = f2bf(gelu_t(acc[hm2*4+mi4][hn*2+ni2][r] + bv)); \
          }                                                                   \
      }                                                                       \
  }                                                                           \
} while (0)

template <int K, int EPI>
__global__ __launch_bounds__(512, 2) void gemm_p(const ush* __restrict__ A,
                                                 const ush* __restrict__ Bm,
                                                 const float* __restrict__ bias,
                                                 void* __restrict__ outp,
                                                 const float* __restrict__ aux,
                                                 int N, int gx, int nwg) {
  __shared__ __attribute__((aligned(16))) ush smem[65536];   // 128 KiB
  constexpr int NT = K / 64;                                 // even (12 or 48)
  const int tid  = threadIdx.x;
  const int w    = tid >> 6;
  const int lane = tid & 63;
  const int quad = lane >> 4;
  const int l16  = lane & 15;
  const int l7   = l16 & 7;
  const int wm   = w >> 2;        // 0..1
  const int wn   = w & 3;         // 0..3

  const int bid = blockIdx.x;
  const int xcd = bid & 7;
  const int cu  = bid >> 3;
  const int tpx = nwg >> 3;       // tiles per XCD (all nwg divisible by 8)
  int pos_c = xcd * tpx + cu;
  const int pos_end = (xcd + 1) * tpx;
  if (pos_c >= pos_end) return;

  int by_c = pos_c / gx, bx_c = pos_c - by_c * gx;

  // pre-swizzled per-lane global source (chunk cb loads global chunk cb^r8)
  const int r8  = lane >> 3;
  const int cb  = lane & 7;
  const int swo = (cb ^ r8) << 3;

  // stage-stream slots: slot1 = step s+1, slot2 = step s+2
  const ush* pA0 = A  + (size_t)(by_c * 256 + r8) * K + swo;
  const ush* pB0 = Bm + (size_t)(bx_c * 256 + r8) * K + swo;
  int pos1 = pos_c, k1 = 0;
  const ush* pA1 = pA0; const ush* pB1 = pB0; bool live1 = true;
  { // advance slot1 to s=1 (NT >= 12, stays in first tile)
    k1 = 64; pA1 += 64; pB1 += 64;
  }
  int pos2 = pos1, k2 = k1;
  const ush* pA2 = pA1; const ush* pB2 = pB1; bool live2 = true;
  ADV2();                          // slot2 -> s=2

  f32x4 acc[8][4];
  ZEROACC();
  bf16x8 af[4][2], bf0[2][2], bf1[2][2];

  // ---- prologue: stage s=0 (all 4 halves) + s=1 (A0,B0) ----
  STAGE2(0, 0, 0, pA0); STAGE2(1, 0, 0, pB0);
  STAGE2(0, 1, 0, pA0); STAGE2(1, 1, 0, pB0);
  STAGE2(0, 0, 1, pA1); STAGE2(1, 0, 1, pB1);
  WAITVM(8);              // A0(0),B0(0) landed
  BARX();

  int kc = 0;             // K-step index within compute tile (parity == kc&1)
  for (;;) {
    STEP(0);
    ++kc;                 // kc was even -> can't be tile end (NT even)
    SHIFT();
    STEP(1);
    if (kc == NT - 1) {
      EPILOGUE();
      pos_c += 32;
      if (pos_c >= pos_end) break;
      kc = 0;
      by_c = pos_c / gx; bx_c = pos_c - by_c * gx;
      ZEROACC();
    } else {
      ++kc;
    }
    SHIFT();
  }
}

// ---------- tiny cross-view attention: one thread per (bp, head, vq) ----------
__global__ __launch_bounds__(256) void attn_kernel(const unsigned short* __restrict__ qs,
                                                   unsigned short* __restrict__ o) {
  int idx = blockIdx.x * 256 + threadIdx.x;   // 25088*32 total
  int vq = idx & 3;
  int h  = (idx >> 2) & 7;
  int bp = idx >> 5;
  const unsigned short* qp = qs + (size_t)bp * 9216 + h * 384 + vq * 96;
  const unsigned short* kp = qs + (size_t)bp * 9216 + 3072 + h * 384;
  const unsigned short* vp = qs + (size_t)bp * 9216 + 6144 + h * 384;
  float s0 = 0.f, s1 = 0.f, s2 = 0.f, s3 = 0.f;
  #pragma unroll
  for (int c = 0; c < 96; c += 8) {
    us8 q8 = *(const us8*)(qp + c);
    us8 k0 = *(const us8*)(kp + c);
    us8 k1 = *(const us8*)(kp + 96 + c);
    us8 k2 = *(const us8*)(kp + 192 + c);
    us8 k3 = *(const us8*)(kp + 288 + c);
    #pragma unroll
    for (int j = 0; j < 8; ++j) {
      float qf = bf2f(q8[j]);
      s0 += qf * bf2f(k0[j]);
      s1 += qf * bf2f(k1[j]);
      s2 += qf * bf2f(k2[j]);
      s3 += qf * bf2f(k3[j]);
    }
  }
  const float scale = 0.10206207261596575f;  // 1/sqrt(96)
  s0 *= scale; s1 *= scale; s2 *= scale; s3 *= scale;
  float m = fmaxf(fmaxf(s0, s1), fmaxf(s2, s3));
  float e0 = __expf(s0 - m), e1 = __expf(s1 - m), e2 = __expf(s2 - m), e3 = __expf(s3 - m);
  float inv = 1.0f / (e0 + e1 + e2 + e3);
  e0 *= inv; e1 *= inv; e2 *= inv; e3 *= inv;
  unsigned short* op = o + (size_t)(bp * 4 + vq) * 768 + h * 96;
  #pragma unroll
  for (int c = 0; c < 96; c += 8) {
    us8 v0 = *(const us8*)(vp + c);
    us8 v1 = *(const us8*)(vp + 96 + c);
    us8 v2 = *(const us8*)(vp + 192 + c);
    us8 v3 = *(const us8*)(vp + 288 + c);
    us8 r;
    #pragma unroll
    for (int j = 0; j < 8; ++j) {
      float val = e0 * bf2f(v0[j]) + e1 * bf2f(v1[j]) + e2 * bf2f(v2[j]) + e3 * bf2f(v3[j]);
      r[j] = f2bf(val);
    }
    *(us8*)(op + c) = r;
  }
}

// ---------- launch ----------
extern "C" void kernel_launch(void* const* d_in, const int* in_sizes, int n_in,
                              void* d_out, int out_size, void* d_ws, size_t ws_size,
                              hipStream_t stream) {
  const float* x         = (const float*)d_in[0];
  const float* norm1_w   = (const float*)d_in[2];
  const float* norm1_b   = (const float*)d_in[3];
  const float* in_proj_w = (const float*)d_in[4];
  const float* in_proj_b = (const float*)d_in[5];
  const float* out_w     = (const float*)d_in[6];
  const float* out_b     = (const float*)d_in[7];
  const float* norm2_w   = (const float*)d_in[8];
  const float* norm2_b   = (const float*)d_in[9];
  const float* ffn_w1    = (const float*)d_in[10];
  const float* ffn_b1    = (const float*)d_in[11];
  const float* ffn_w2    = (const float*)d_in[12];
  const float* ffn_b2    = (const float*)d_in[13];
  float* out = (float*)d_out;

  char* ws = (char*)d_ws;
  unsigned short* wq = (unsigned short*)ws;                           // 616.6 MB
  unsigned short* wh = (unsigned short*)(ws + 616562688u);            // 154.1 MB
  unsigned short* wB = (unsigned short*)(ws + 616562688u + 154140672u);
  unsigned short* wIn  = wB;
  unsigned short* wOut = wB + 1769472;
  unsigned short* wF1  = wOut + 589824;
  unsigned short* wF2  = wF1 + 2359296;

  conv_f32_bf16<<<(442368 + 255) / 256, 256, 0, stream>>>(in_proj_w, wIn, 442368);
  conv_f32_bf16<<<(147456 + 255) / 256, 256, 0, stream>>>(out_w, wOut, 147456);
  conv_f32_bf16<<<(589824 + 255) / 256, 256, 0, stream>>>(ffn_w1, wF1, 589824);
  conv_f32_bf16<<<(589824 + 255) / 256, 256, 0, stream>>>(ffn_w2, wF2, 589824);

  // LN1: x (permuted read) -> wh
  ln_kernel<<<25088, 256, 0, stream>>>(x, norm1_w, norm1_b, wh);
  // QKV: wh(100352x768) @ in_proj_w^T -> wq (attention layout)
  gemm_p<768, 0><<<256, 512, 0, stream>>>(wh, wIn, in_proj_b, (void*)wq, nullptr, 2304, 9, 3528);
  // attention: wq -> wh (o, bf16 rows)
  attn_kernel<<<3136, 256, 0, stream>>>(wq, wh);
  // out-proj + residual(x): wh @ out_w^T -> d_out fp32 (unfolded)
  gemm_p<768, 1><<<256, 512, 0, stream>>>(wh, wOut, out_b, (void*)out, x, 768, 3, 1176);
  // LN2: d_out (permuted read) -> wh
  ln_kernel<<<25088, 256, 0, stream>>>(out, norm2_w, norm2_b, wh);
  // FFN1 + gelu: wh @ ffn_w1^T -> wq bf16 row-major
  gemm_p<768, 2><<<256, 512, 0, stream>>>(wh, wF1, ffn_b1, (void*)wq, nullptr, 3072, 12, 4704);
  // FFN2 + residual(d_out): wq(100352x3072) @ ffn_w2^T -> d_out fp32
  gemm_p<3072, 3><<<256, 512, 0, stream>>>(wq, wF2, ffn_b2, (void*)out, out, 768, 3, 1176);

  (void)in_sizes; (void)n_in; (void)out_size; (void)ws_size;
}

// Round 3
// 2690.957 us; speedup vs baseline: 1.1066x; 1.1066x over previous
//
#include <hip/hip_runtime.h>
#include <hip/hip_bf16.h>
#include <math.h>

// ---------- types ----------
typedef __bf16 bf16x8 __attribute__((ext_vector_type(8)));
typedef float  f32x4  __attribute__((ext_vector_type(4)));
typedef unsigned short us8 __attribute__((ext_vector_type(8)));
typedef unsigned short us4 __attribute__((ext_vector_type(4)));
typedef unsigned short ush;

__device__ __forceinline__ unsigned short f2bf(float x) {
  unsigned int u = __float_as_uint(x);
  u += 0x7FFFu + ((u >> 16) & 1u);          // RNE
  return (unsigned short)(u >> 16);
}
__device__ __forceinline__ float bf2f(unsigned short v) {
  return __uint_as_float(((unsigned int)v) << 16);
}
// tanh-form GELU: max |diff vs erf-gelu| ~1e-3, harmless vs threshold
__device__ __forceinline__ float gelu_t(float x) {
  float y = 0.7978845608028654f * x * (1.0f + 0.044715f * x * x);
  float e = __expf(2.0f * y);
  return x - x / (e + 1.0f);
}

// Problem constants: B=32, V=4, P=784, D=768; rows n = bp*4+v, bp=b*784+p
// NROW = 100352 = 392*256
//
// BLOCKED A-LAYOUT (new this round): every GEMM A-operand is stored as
// contiguous 32 KB staging tiles: tile(by, kstep) holds rows r=0..255,
// k-elems kstep*64..+63, at in-tile ush offset
//   r*64 + ((sub16 ^ (r&7)) << 3) + (k&7),  sub16 = (k>>3)&7.
// This is byte-identical to the GEMM's swizzled LDS image, so the A-stage
// is a linear 1KB-per-lane-contiguous global_load_lds (DRAM-friendly) and
// the ds_read side is unchanged. Producers (ln, attn, FFN1-epilogue)
// write this layout directly.

// ---------- f32 -> bf16 convert (weights) ----------
__global__ __launch_bounds__(256) void conv_f32_bf16(const float* __restrict__ s,
                                                     unsigned short* __restrict__ d, int n4) {
  int i = blockIdx.x * 256 + threadIdx.x;
  if (i >= n4) return;
  float4 f = ((const float4*)s)[i];
  ushort4 u;
  u.x = f2bf(f.x); u.y = f2bf(f.y); u.z = f2bf(f.z); u.w = f2bf(f.w);
  ((ushort4*)d)[i] = u;
}

// ---------- LayerNorm: read permuted fp32 row, write blocked-A bf16 ----------
__global__ __launch_bounds__(256) void ln_kernel(const float* __restrict__ src,
                                                 const float* __restrict__ w,
                                                 const float* __restrict__ b,
                                                 unsigned short* __restrict__ dst) {
  const int wv = threadIdx.x >> 6;
  const int lane = threadIdx.x & 63;
  const int n = blockIdx.x * 4 + wv;            // token row 0..100351
  const int bp = n >> 2, v = n & 3;
  const int bb = bp / 784, p = bp - bb * 784;
  const float* row = src + ((size_t)bb * 3136 + (size_t)v * 784 + p) * 768;
  float4 x0 = ((const float4*)row)[lane];
  float4 x1 = ((const float4*)row)[lane + 64];
  float4 x2 = ((const float4*)row)[lane + 128];
  float s  = x0.x + x0.y + x0.z + x0.w + x1.x + x1.y + x1.z + x1.w
           + x2.x + x2.y + x2.z + x2.w;
  float ss = x0.x*x0.x + x0.y*x0.y + x0.z*x0.z + x0.w*x0.w
           + x1.x*x1.x + x1.y*x1.y + x1.z*x1.z + x1.w*x1.w
           + x2.x*x2.x + x2.y*x2.y + x2.z*x2.z + x2.w*x2.w;
  #pragma unroll
  for (int off = 32; off > 0; off >>= 1) {
    s  += __shfl_xor(s,  off, 64);
    ss += __shfl_xor(ss, off, 64);
  }
  const float mu   = s * (1.0f / 768.0f);
  const float rstd = rsqrtf(ss * (1.0f / 768.0f) - mu * mu + 1e-5f);
  // blocked-A store: k = (lane + seg*64)*4 ; kstep=(lane>>4)+seg*4 ;
  // sub16=(lane>>1)&7 ; k&7=(lane&1)*4 ; r = n&255
  const int r = n & 255;
  unsigned short* bb2 = dst + (((size_t)(n >> 8) * 12) << 14) + r * 64
                      + ((((lane >> 1) & 7) ^ (r & 7)) << 3) + ((lane & 1) << 2);
  #pragma unroll
  for (int seg = 0; seg < 3; ++seg) {
    float4 xs = (seg == 0) ? x0 : (seg == 1) ? x1 : x2;
    float4 w4 = ((const float4*)w)[lane + seg * 64];
    float4 b4 = ((const float4*)b)[lane + seg * 64];
    us4 u;
    u[0] = f2bf((xs.x - mu) * rstd * w4.x + b4.x);
    u[1] = f2bf((xs.y - mu) * rstd * w4.y + b4.y);
    u[2] = f2bf((xs.z - mu) * rstd * w4.z + b4.z);
    u[3] = f2bf((xs.w - mu) * rstd * w4.w + b4.w);
    *(us4*)(bb2 + (((size_t)((lane >> 4) + seg * 4)) << 14)) = u;
  }
}

// =====================================================================
// GEMM: C = A(blocked bf16, MxK) * B(bf16, NxK)^T + epilogue
// 256x256 tile, BK=64, 8 waves (2M x 4N), 16x16x32 bf16 MFMA,
// 8-phase counted-vmcnt schedule (R1 structure, verified), XOR-swizzled
// LDS for conflict-free ds_read_b128.
// A-stage: linear 32KB blocked-tile copy (lane-contiguous, DRAM-friendly).
// B-stage: pre-swizzled per-lane global source (B is small & L2-hot).
// =====================================================================

#define BARX() do { asm volatile("" ::: "memory"); \
                    __builtin_amdgcn_s_barrier();  \
                    asm volatile("" ::: "memory"); } while (0)
#define WAITVM(N) asm volatile("s_waitcnt vmcnt(" #N ")" ::: "memory")

// stage one 128-row half (16 KiB) of blocked A tile TT (linear copy)
#define STAGE_A(HALF, TT) do {                                                \
  _Pragma("unroll")                                                           \
  for (int _j = 0; _j < 2; ++_j) {                                            \
    const int _ob = ((HALF) << 13) + (w << 10) + (_j << 9);                   \
    __builtin_amdgcn_global_load_lds(                                         \
        (const __attribute__((address_space(1))) void*)(                      \
            gAt + (((size_t)(TT)) << 14) + _ob + lnoff8),                     \
        (__attribute__((address_space(3))) void*)(                            \
            smem + ((((TT) & 1)) << 15) + _ob), 16, 0, 0);                    \
  }                                                                           \
} while (0)

// stage one 128-row half (16 KiB) of B for K-step TT (pre-swizzled source)
#define STAGE_B(HALF, TT) do {                                                \
  const int _l0 = ((((TT) & 1)) << 15) + 16384 + ((HALF) << 13) + (w << 9);   \
  const ush* _g = gB + (size_t)(((HALF) << 7) + (w << 3)) * K                 \
                + (((size_t)(TT)) << 6);                                      \
  __builtin_amdgcn_global_load_lds(                                           \
      (const __attribute__((address_space(1))) void*)_g,                      \
      (__attribute__((address_space(3))) void*)(smem + _l0), 16, 0, 0);       \
  __builtin_amdgcn_global_load_lds(                                           \
      (const __attribute__((address_space(1))) void*)(_g + ((size_t)K << 6)), \
      (__attribute__((address_space(3))) void*)(smem + _l0 + 4096), 16, 0, 0);\
} while (0)

#define LDA(HM) do {                                                          \
  _Pragma("unroll")                                                           \
  for (int mi4 = 0; mi4 < 4; ++mi4) {                                         \
    const int m = wm * 64 + (HM) * 128 + mi4 * 16 + l16;                      \
    _Pragma("unroll")                                                         \
    for (int kk = 0; kk < 2; ++kk) {                                          \
      const int q = kk * 4 + quad;                                            \
      af[mi4][kk] = *(const bf16x8*)(smem + aofs + m * 64 + ((q ^ (m & 7)) << 3)); \
    }                                                                         \
  }                                                                           \
} while (0)

#define LDB(HN, BF) do {                                                      \
  _Pragma("unroll")                                                           \
  for (int ni2 = 0; ni2 < 2; ++ni2) {                                         \
    const int n = wn * 32 + (HN) * 128 + ni2 * 16 + l16;                      \
    _Pragma("unroll")                                                         \
    for (int kk = 0; kk < 2; ++kk) {                                          \
      const int q = kk * 4 + quad;                                            \
      BF[ni2][kk] = *(const bf16x8*)(smem + bofs + n * 64 + ((q ^ (n & 7)) << 3)); \
    }                                                                         \
  }                                                                           \
} while (0)

#define MFMAC(HM, HN, BF) do {                                                \
  __builtin_amdgcn_s_setprio(1);                                              \
  _Pragma("unroll")                                                           \
  for (int mi4 = 0; mi4 < 4; ++mi4)                                           \
    _Pragma("unroll")                                                         \
    for (int ni2 = 0; ni2 < 2; ++ni2)                                         \
      _Pragma("unroll")                                                       \
      for (int kk = 0; kk < 2; ++kk)                                          \
        acc[(HM)*4 + mi4][(HN)*2 + ni2] = __builtin_amdgcn_mfma_f32_16x16x32_bf16( \
            af[mi4][kk], BF[ni2][kk], acc[(HM)*4 + mi4][(HN)*2 + ni2], 0, 0, 0); \
  __builtin_amdgcn_s_setprio(0);                                              \
} while (0)

// EPI: 0 = +bias -> qkv bf16 [bp][seg][h][v][96]
//      1/3 = +bias +aux residual -> fp32 (unfolded addr)
//      2 = +bias, gelu -> bf16 blocked-A layout (NT=48, for FFN2)
template <int K, int EPI>
__global__ __launch_bounds__(512, 2) void gemm256(const ush* __restrict__ A,
                                                  const ush* __restrict__ Bm,
                                                  const float* __restrict__ bias,
                                                  void* __restrict__ outp,
                                                  const float* __restrict__ aux,
                                                  int N) {
  __shared__ __attribute__((aligned(16))) ush smem[65536];   // 128 KiB
  constexpr int NT = K / 64;
  const int tid  = threadIdx.x;
  const int w    = tid >> 6;
  const int lane = tid & 63;
  const int quad = lane >> 4;
  const int l16  = lane & 15;
  const int wm   = w >> 2;        // 0..1
  const int wn   = w & 3;         // 0..3

  // XCD-aware bijective remap: each XCD owns nwg/8 consecutive (by,bx) in
  // bx-fastest order -> A row-panel reused across all bx within one L2.
  const int gx   = gridDim.x;
  const int nwg  = gx * 392;
  const int flat = blockIdx.y * gx + blockIdx.x;
  const int xcd  = flat & 7;
  const int pos  = xcd * (nwg >> 3) + (flat >> 3);
  const int by   = pos / gx;
  const int bx   = pos - by * gx;

  // A: blocked-tile base for this row-panel; lane-contiguous 16B pieces
  const ush* gAt   = A + (((size_t)by * NT) << 14);
  const int  lnoff8 = lane << 3;                 // lane*16B in ush

  // B: pre-swizzled per-lane global source (chunk cb loads chunk cb^r8)
  const int r8  = lane >> 3;
  const int cb  = lane & 7;
  const int swo = (cb ^ r8) << 3;
  const ush* gB = Bm + (size_t)(bx * 256 + r8) * K + swo;

  f32x4 acc[8][4];
  #pragma unroll
  for (int i = 0; i < 8; ++i)
    #pragma unroll
    for (int j = 0; j < 4; ++j) {
      f32x4 z = {0.0f, 0.0f, 0.0f, 0.0f};
      acc[i][j] = z;
    }
  bf16x8 af[4][2], bf0[2][2], bf1[2][2];

  // ---- prologue: stage halves A0,B0,A1,B1(t0), A0,B0(t1) ----
  STAGE_A(0, 0); STAGE_B(0, 0); STAGE_A(1, 0);
  STAGE_B(1, 0); STAGE_A(0, 1); STAGE_B(0, 1);
  WAITVM(8);              // A0(0),B0(0) landed (4 newest halves may fly)
  BARX();

  #pragma unroll 2
  for (int t = 0; t < NT; ++t) {
    const int aofs = (t & 1) << 15;
    const int bofs = aofs + 16384;
    // ---- q0: hm=0, hn=0 ----
    LDA(0); LDB(0, bf0);
    if (t <= NT - 2) STAGE_A(1, t + 1);      // A1(t+1) -> other buf
    BARX();
    MFMAC(0, 0, bf0);
    if (t < NT - 1) { WAITVM(6); } else { WAITVM(0); }  // A1(t),B1(t) landed
    BARX();
    // ---- q1: hm=0, hn=1 ----
    LDB(1, bf1);
    if (t <= NT - 2) STAGE_B(1, t + 1);      // B1(t+1) -> other buf
    BARX();
    MFMAC(0, 1, bf1);
    BARX();
    // ---- q2: hm=1, hn=0 ----
    LDA(1);
    if (t <= NT - 3) STAGE_A(0, t + 2);      // A0(t+2) -> this buf (half0 free)
    BARX();
    MFMAC(1, 0, bf0);
    BARX();
    // ---- q3: hm=1, hn=1 (B frags reused, no ds_reads) ----
    if (t <= NT - 3) STAGE_B(0, t + 2);      // B0(t+2) -> this buf (half0 free)
    BARX();
    MFMAC(1, 1, bf1);
    if (t <= NT - 3)      { WAITVM(8); }     // A0,B0(t+1) landed
    else if (t == NT - 2) { WAITVM(4); }
    BARX();
  }

  // ---- epilogue: 4 stages of 64 rows x 256 cols via LDS (stride 260) ----
  float* lsm = (float*)smem;
  #pragma unroll
  for (int s = 0; s < 4; ++s) {
    if (wm == (s & 1)) {
      const int hm = s >> 1;                 // compile-time (s unrolled)
      #pragma unroll
      for (int mi4 = 0; mi4 < 4; ++mi4)
        #pragma unroll
        for (int ni = 0; ni < 4; ++ni) {
          const int col = wn * 32 + (ni >> 1) * 128 + (ni & 1) * 16 + l16;
          #pragma unroll
          for (int r = 0; r < 4; ++r) {
            const int row_l = mi4 * 16 + quad * 4 + r;
            lsm[row_l * 260 + col] = acc[hm * 4 + mi4][ni][r];
          }
        }
    }
    __syncthreads();
    #pragma unroll
    for (int j = 0; j < 8; ++j) {
      const int cc    = tid + 512 * j;       // 0..4095 = 64 rows x 64 chunks
      const int row_l = cc >> 6;
      const int c4    = (cc & 63) << 2;
      f32x4 vv = *(const f32x4*)&lsm[row_l * 260 + c4];
      const int rr    = by * 256 + s * 64 + row_l;
      const int col_g = bx * 256 + c4;
      f32x4 b4 = *(const f32x4*)&bias[col_g];
      vv += b4;
      if (EPI == 0) {
        const int seg = col_g / 768;
        const int c2  = col_g - seg * 768;
        const int hh  = c2 / 96;
        const int dd  = c2 - hh * 96;
        const int bp = rr >> 2, v = rr & 3;
        us4 u = { f2bf(vv[0]), f2bf(vv[1]), f2bf(vv[2]), f2bf(vv[3]) };
        *(us4*)((unsigned short*)outp + (size_t)bp * 9216 + seg * 3072 + hh * 384 + v * 96 + dd) = u;
      } else if (EPI == 1 || EPI == 3) {
        const int bp = rr >> 2, v = rr & 3;
        const int bb = bp / 784, p = bp - bb * 784;
        const size_t addr = ((size_t)bb * 3136 + (size_t)v * 784 + p) * 768 + col_g;
        f32x4 a4 = *(const f32x4*)(aux + addr);
        vv += a4;
        *(f32x4*)((float*)outp + addr) = vv;
      } else { // EPI == 2: gelu -> bf16, blocked-A layout (NT=48) for FFN2
        us4 u = { f2bf(gelu_t(vv[0])), f2bf(gelu_t(vv[1])),
                  f2bf(gelu_t(vv[2])), f2bf(gelu_t(vv[3])) };
        const int rb = rr & 255;
        *(us4*)((unsigned short*)outp
               + (((size_t)(rr >> 8) * 48 + (col_g >> 6)) << 14)
               + rb * 64 + ((((col_g >> 3) & 7) ^ (rb & 7)) << 3) + (col_g & 7)) = u;
      }
    }
    __syncthreads();
  }
}

// ---------- tiny cross-view attention: one thread per (bp, head, vq) ----------
// output: blocked-A layout (NT=12) for the out-proj GEMM
__global__ __launch_bounds__(256) void attn_kernel(const unsigned short* __restrict__ qs,
                                                   unsigned short* __restrict__ o) {
  int idx = blockIdx.x * 256 + threadIdx.x;   // 25088*32 total
  int vq = idx & 3;
  int h  = (idx >> 2) & 7;
  int bp = idx >> 5;
  const unsigned short* qp = qs + (size_t)bp * 9216 + h * 384 + vq * 96;
  const unsigned short* kp = qs + (size_t)bp * 9216 + 3072 + h * 384;
  const unsigned short* vp = qs + (size_t)bp * 9216 + 6144 + h * 384;
  float s0 = 0.f, s1 = 0.f, s2 = 0.f, s3 = 0.f;
  #pragma unroll
  for (int c = 0; c < 96; c += 8) {
    us8 q8 = *(const us8*)(qp + c);
    us8 k0 = *(const us8*)(kp + c);
    us8 k1 = *(const us8*)(kp + 96 + c);
    us8 k2 = *(const us8*)(kp + 192 + c);
    us8 k3 = *(const us8*)(kp + 288 + c);
    #pragma unroll
    for (int j = 0; j < 8; ++j) {
      float qf = bf2f(q8[j]);
      s0 += qf * bf2f(k0[j]);
      s1 += qf * bf2f(k1[j]);
      s2 += qf * bf2f(k2[j]);
      s3 += qf * bf2f(k3[j]);
    }
  }
  const float scale = 0.10206207261596575f;  // 1/sqrt(96)
  s0 *= scale; s1 *= scale; s2 *= scale; s3 *= scale;
  float m = fmaxf(fmaxf(s0, s1), fmaxf(s2, s3));
  float e0 = __expf(s0 - m), e1 = __expf(s1 - m), e2 = __expf(s2 - m), e3 = __expf(s3 - m);
  float inv = 1.0f / (e0 + e1 + e2 + e3);
  e0 *= inv; e1 *= inv; e2 *= inv; e3 *= inv;
  const int rn = bp * 4 + vq;
  const int rr2 = rn & 255;
  unsigned short* ob = o + (((size_t)(rn >> 8) * 12) << 14) + rr2 * 64;
  #pragma unroll
  for (int c = 0; c < 96; c += 8) {
    us8 v0 = *(const us8*)(vp + c);
    us8 v1 = *(const us8*)(vp + 96 + c);
    us8 v2 = *(const us8*)(vp + 192 + c);
    us8 v3 = *(const us8*)(vp + 288 + c);
    us8 r;
    #pragma unroll
    for (int j = 0; j < 8; ++j) {
      float val = e0 * bf2f(v0[j]) + e1 * bf2f(v1[j]) + e2 * bf2f(v2[j]) + e3 * bf2f(v3[j]);
      r[j] = f2bf(val);
    }
    const int k = h * 96 + c;
    *(us8*)(ob + (((size_t)(k >> 6)) << 14) + ((((k >> 3) & 7) ^ (rr2 & 7)) << 3)) = r;
  }
}

// ---------- launch ----------
extern "C" void kernel_launch(void* const* d_in, const int* in_sizes, int n_in,
                              void* d_out, int out_size, void* d_ws, size_t ws_size,
                              hipStream_t stream) {
  const float* x         = (const float*)d_in[0];
  const float* norm1_w   = (const float*)d_in[2];
  const float* norm1_b   = (const float*)d_in[3];
  const float* in_proj_w = (const float*)d_in[4];
  const float* in_proj_b = (const float*)d_in[5];
  const float* out_w     = (const float*)d_in[6];
  const float* out_b     = (const float*)d_in[7];
  const float* norm2_w   = (const float*)d_in[8];
  const float* norm2_b   = (const float*)d_in[9];
  const float* ffn_w1    = (const float*)d_in[10];
  const float* ffn_b1    = (const float*)d_in[11];
  const float* ffn_w2    = (const float*)d_in[12];
  const float* ffn_b2    = (const float*)d_in[13];
  float* out = (float*)d_out;

  char* ws = (char*)d_ws;
  unsigned short* wq = (unsigned short*)ws;                           // 616.6 MB
  unsigned short* wh = (unsigned short*)(ws + 616562688u);            // 154.1 MB
  unsigned short* wB = (unsigned short*)(ws + 616562688u + 154140672u);
  unsigned short* wIn  = wB;
  unsigned short* wOut = wB + 1769472;
  unsigned short* wF1  = wOut + 589824;
  unsigned short* wF2  = wF1 + 2359296;

  conv_f32_bf16<<<(442368 + 255) / 256, 256, 0, stream>>>(in_proj_w, wIn, 442368);
  conv_f32_bf16<<<(147456 + 255) / 256, 256, 0, stream>>>(out_w, wOut, 147456);
  conv_f32_bf16<<<(589824 + 255) / 256, 256, 0, stream>>>(ffn_w1, wF1, 589824);
  conv_f32_bf16<<<(589824 + 255) / 256, 256, 0, stream>>>(ffn_w2, wF2, 589824);

  // LN1: x (permuted read) -> wh (blocked-A, NT=12)
  ln_kernel<<<25088, 256, 0, stream>>>(x, norm1_w, norm1_b, wh);
  // QKV: wh(100352x768) @ in_proj_w^T -> wq (attention layout)
  gemm256<768, 0><<<dim3(9, 392), 512, 0, stream>>>(wh, wIn, in_proj_b, (void*)wq, nullptr, 2304);
  // attention: wq -> wh (o, blocked-A NT=12)
  attn_kernel<<<3136, 256, 0, stream>>>(wq, wh);
  // out-proj + residual(x): wh @ out_w^T -> d_out fp32 (unfolded)
  gemm256<768, 1><<<dim3(3, 392), 512, 0, stream>>>(wh, wOut, out_b, (void*)out, x, 768);
  // LN2: d_out (permuted read) -> wh (blocked-A, NT=12)
  ln_kernel<<<25088, 256, 0, stream>>>(out, norm2_w, norm2_b, wh);
  // FFN1 + gelu: wh @ ffn_w1^T -> wq (blocked-A, NT=48)
  gemm256<768, 2><<<dim3(12, 392), 512, 0, stream>>>(wh, wF1, ffn_b1, (void*)wq, nullptr, 3072);
  // FFN2 + residual(d_out): wq(100352x3072 blocked) @ ffn_w2^T -> d_out fp32
  gemm256<3072, 3><<<dim3(3, 392), 512, 0, stream>>>(wq, wF2, ffn_b2, (void*)out, out, 768);

  (void)in_sizes; (void)n_in; (void)out_size; (void)ws_size;
}